// Round 1
// baseline (70.739 us; speedup 1.0000x reference)
//
#include <hip/hip_runtime.h>
#include <math.h>

#define N_LABELS 50
#define NCLS 80

__device__ __constant__ float d_anchors[9][2] = {
    {10.f,13.f},{16.f,30.f},{33.f,23.f},{30.f,61.f},{62.f,45.f},
    {59.f,119.f},{116.f,90.f},{156.f,198.f},{373.f,326.f}
};

__device__ __forceinline__ float bce_logits(float x, float z) {
    // max(x,0) - x*z + log1p(exp(-|x|))
    return fmaxf(x, 0.f) - x * z + log1pf(expf(-fabsf(x)));
}

struct Lab {
    float tx, ty, tw, th;   // truth box in grid units (cxcywh)
    float lw, lh;           // log(tw/aw), log(th/ah) for best anchor
    float sc;               // sqrt(2 - tw*th/(H*W))
    int   lin;              // matched cell index, -1 if not matched to this layer
    int   cls;
};

template<int H, int W, int STRIDE, int GROUP>
__device__ __forceinline__ void layer_loss_block(
        const float* __restrict__ out,
        const float* __restrict__ targets,
        float* __restrict__ loss_out,
        int b, int chunk)
{
    constexpr int HW = H * W;
    constexpr int NC = 3 * HW;
    const float LOG2F = 0.6931471805599453f;

    __shared__ Lab labs[N_LABELS];
    int tid = threadIdx.x;

    if (tid < N_LABELS) {
        const float* lp = targets + ((size_t)b * N_LABELS + tid) * 5;
        float cls = lp[0], x = lp[1], y = lp[2], w = lp[3], h = lp[4];
        float tx = x * (float)W, ty = y * (float)H;
        float tw = w * (float)W, th = h * (float)H;
        float tarea = tw * th;
        // anchor IoU against all 9 reference anchors (origin-anchored)
        float best_iou = -1.f; int best = 0;
        #pragma unroll
        for (int k = 0; k < 9; ++k) {
            float rw = d_anchors[k][0] / (float)STRIDE;
            float rh = d_anchors[k][1] / (float)STRIDE;
            float mx = fminf(tw, rw), my = fminf(th, rh);
            float inter = (mx > 0.f && my > 0.f) ? mx * my : 0.f;
            float iou = inter / (tarea + rw * rh - inter);
            if (iou > best_iou) { best_iou = iou; best = k; }
        }
        int bn = best % 3;
        bool matched = (best / 3) == GROUP;
        int ti = (int)tx, tj = (int)ty;
        float aw = d_anchors[GROUP * 3 + bn][0] / (float)STRIDE;
        float ah = d_anchors[GROUP * 3 + bn][1] / (float)STRIDE;
        Lab L;
        L.tx = tx; L.ty = ty; L.tw = tw; L.th = th;
        L.lw = logf(tw / aw + 1e-16f);
        L.lh = logf(th / ah + 1e-16f);
        L.sc = sqrtf(2.f - tarea / (float)HW);
        L.lin = matched ? (bn * H + tj) * W + ti : -1;
        L.cls = (int)cls;
        labs[tid] = L;
    }
    __syncthreads();

    int cell = chunk * 256 + tid;
    float lsum = 0.f;
    if (cell < NC) {
        int a = cell / HW;
        int rem = cell - a * HW;
        int hh = rem / W;
        int ww = rem - hh * W;
        const float* base = out + ((size_t)b * 255 + a * 85) * HW + rem;
        float c0 = base[0];
        float c1 = base[(size_t)HW];
        float c2 = base[2 * (size_t)HW];
        float c3 = base[3 * (size_t)HW];
        float c4 = base[4 * (size_t)HW];

        float aw = d_anchors[GROUP * 3 + a][0] / (float)STRIDE;
        float ah = d_anchors[GROUP * 3 + a][1] / (float)STRIDE;
        float px = 1.f / (1.f + expf(-c0)) + (float)ww;
        float py = 1.f / (1.f + expf(-c1)) + (float)hh;
        float pw = expf(c2) * aw;
        float ph = expf(c3) * ah;
        float parea = pw * ph;
        float hx = 0.5f * pw, hy = 0.5f * ph;

        float maxiou = -1e30f;
        int ml = -1;  // last label matched to this cell (numpy last-write-wins)
        for (int l = 0; l < N_LABELS; ++l) {
            Lab L = labs[l];
            float thx = 0.5f * L.tw, thy = 0.5f * L.th;
            float tlx = fmaxf(px - hx, L.tx - thx);
            float tly = fmaxf(py - hy, L.ty - thy);
            float brx = fminf(px + hx, L.tx + thx);
            float bry = fminf(py + hy, L.ty + thy);
            float inter = (tlx < brx && tly < bry) ? (brx - tlx) * (bry - tly) : 0.f;
            float iou = inter / (parea + L.tw * L.th - inter);
            maxiou = fmaxf(maxiou, iou);
            if (L.lin == cell) ml = l;
        }

        if (ml >= 0) {
            Lab L = labs[ml];
            // obj: forced 1 at matched cell, target 1
            lsum += bce_logits(c4, 1.f);
            float s2 = L.sc * L.sc;
            float txf = L.tx - (float)(int)L.tx;
            float tyf = L.ty - (float)(int)L.ty;
            lsum += (bce_logits(c0, txf) + bce_logits(c1, tyf)) * s2;
            float dw = c2 - L.lw;
            float dh = c3 - L.lh;
            lsum += 0.5f * (dw * dw + dh * dh) * s2;
            for (int c = 0; c < NCLS; ++c) {
                float lg = base[(5 + (size_t)c) * HW];
                lsum += bce_logits(lg, (c == L.cls) ? 1.f : 0.f);
            }
        } else {
            // obj: 1 if maxiou <= thresh (bce(logit,0)), else ignored -> bce(0,0)=log2
            lsum += (maxiou <= 0.7f) ? bce_logits(c4, 0.f) : LOG2F;
            // cls: sel=0 -> bce(0,0)*80
            lsum += 80.f * LOG2F;
        }
    }

    // block reduction: wave64 shuffle then LDS
    for (int off = 32; off > 0; off >>= 1)
        lsum += __shfl_down(lsum, off);
    __shared__ float wsums[4];
    int wid = tid >> 6, lane = tid & 63;
    if (lane == 0) wsums[wid] = lsum;
    __syncthreads();
    if (tid == 0)
        atomicAdd(loss_out, wsums[0] + wsums[1] + wsums[2] + wsums[3]);
}

// Layer block counts: L0 (19x19): NC=1083, chunks=5, 5*16=80 blocks
//                     L1 (38x38): NC=4332, chunks=17, 17*16=272 blocks
//                     L2 (76x76): NC=17328, chunks=68, 68*16=1088 blocks
__global__ __launch_bounds__(256) void yolo_main(
        const float* __restrict__ o0, const float* __restrict__ o1,
        const float* __restrict__ o2, const float* __restrict__ tgt,
        float* __restrict__ loss)
{
    int bid = blockIdx.x;
    if (bid < 80) {
        layer_loss_block<19, 19, 32, 2>(o0, tgt, loss, bid / 5, bid % 5);
    } else if (bid < 352) {
        int id = bid - 80;
        layer_loss_block<38, 38, 16, 1>(o1, tgt, loss, id / 17, id % 17);
    } else {
        int id = bid - 352;
        layer_loss_block<76, 76, 8, 0>(o2, tgt, loss, id / 68, id % 68);
    }
}

__global__ void zero_out_kernel(float* p) { *p = 0.f; }

extern "C" void kernel_launch(void* const* d_in, const int* in_sizes, int n_in,
                              void* d_out, int out_size, void* d_ws, size_t ws_size,
                              hipStream_t stream) {
    const float* o0  = (const float*)d_in[0];
    const float* o1  = (const float*)d_in[1];
    const float* o2  = (const float*)d_in[2];
    const float* tgt = (const float*)d_in[3];
    float* loss = (float*)d_out;
    zero_out_kernel<<<1, 1, 0, stream>>>(loss);
    yolo_main<<<1440, 256, 0, stream>>>(o0, o1, o2, tgt, loss);
}

// Round 2
// 32.891 us; speedup vs baseline: 2.1507x; 2.1507x over previous
//
#include <hip/hip_runtime.h>
#include <math.h>

#define N_LABELS 50
#define NCLS 80
#define LOG2C 0.693147180559945f

__device__ __constant__ float d_anchors[9][2] = {
    {10.f,13.f},{16.f,30.f},{33.f,23.f},{30.f,61.f},{62.f,45.f},
    {59.f,119.f},{116.f,90.f},{156.f,198.f},{373.f,326.f}
};

__device__ __forceinline__ float softplus_f(float x) {      // == bce(x, 0)
    return fmaxf(x, 0.f) + __logf(1.f + __expf(-fabsf(x)));
}
__device__ __forceinline__ float bce_f(float x, float z) {
    return fmaxf(x, 0.f) - x * z + __logf(1.f + __expf(-fabsf(x)));
}
__device__ __forceinline__ float sigmoid_f(float x) {
    return __builtin_amdgcn_rcpf(1.f + __expf(-x));
}

__device__ __forceinline__ void block_reduce_atomic(float v, float* wsums, float* out) {
    #pragma unroll
    for (int off = 32; off > 0; off >>= 1)
        v += __shfl_down(v, off);
    int tid = threadIdx.x;
    if ((tid & 63) == 0) wsums[tid >> 6] = v;
    __syncthreads();
    if (tid == 0) atomicAdd(out, wsums[0] + wsums[1] + wsums[2] + wsums[3]);
}

// ---------------- main uniform pass: every cell, no divergence ----------------
template<int H, int W, int STRIDE, int GROUP>
__device__ __forceinline__ void main_part(const float* __restrict__ out,
        const float* __restrict__ tgt, float* __restrict__ loss,
        int b, int chunk, float4* sbox, float* sa, float* wsums)
{
    constexpr int HW = H * W;
    constexpr int NC = 3 * HW;
    int tid = threadIdx.x;

    if (tid < N_LABELS) {
        const float* lp = tgt + ((size_t)b * N_LABELS + tid) * 5;
        float tx = lp[1] * (float)W, ty = lp[2] * (float)H;
        float tw = lp[3] * (float)W, th = lp[4] * (float)H;
        sbox[tid] = make_float4(tx - 0.5f*tw, ty - 0.5f*th, tx + 0.5f*tw, ty + 0.5f*th);
        sa[tid] = tw * th * (0.7f / 1.7f);
    }
    __syncthreads();

    const float* ob = out + (size_t)b * 255 * HW;
    int c0i = chunk * 512 + tid;
    float x0[2], x1[2], y0[2], y1[2], p07[2], c4v[2], whb[2];
    bool valid[2], ign[2];

    #pragma unroll
    for (int k = 0; k < 2; ++k) {
        int cell = c0i + k * 256;
        valid[k] = (cell < NC);
        int cc = valid[k] ? cell : 0;
        int a = cc / HW, rem = cc - a * HW;
        int hh = rem / W, ww = rem - hh * W;
        const float* base = ob + (size_t)a * 85 * HW + rem;
        float c0 = base[0];
        float c1 = base[HW];
        float c2 = base[2 * (size_t)HW];
        float c3 = base[3 * (size_t)HW];
        c4v[k] = base[4 * (size_t)HW];
        float aw = d_anchors[GROUP*3 + a][0] * (1.f / (float)STRIDE);
        float ah = d_anchors[GROUP*3 + a][1] * (1.f / (float)STRIDE);
        float pw = __expf(c2) * aw, ph = __expf(c3) * ah;
        float px = sigmoid_f(c0) + (float)ww;
        float py = sigmoid_f(c1) + (float)hh;
        x0[k] = px - 0.5f*pw; x1[k] = px + 0.5f*pw;
        y0[k] = py - 0.5f*ph; y1[k] = py + 0.5f*ph;
        p07[k] = pw * ph * (0.7f / 1.7f);
        whb[k] = 0.5f * (c2*c2 + c3*c3);      // unmasked wh (warm-up prior) term
        ign[k] = false;
    }

    for (int l = 0; l < N_LABELS; ++l) {
        float4 tb = sbox[l];
        float ta = sa[l];
        #pragma unroll
        for (int k = 0; k < 2; ++k) {
            float w_ = fminf(x1[k], tb.z) - fmaxf(x0[k], tb.x);
            float h_ = fminf(y1[k], tb.w) - fmaxf(y0[k], tb.y);
            // iou > 0.7  <=>  inter > 0.7/1.7 * (parea + tarea)   (no division)
            bool hit = (w_ > 0.f) && (h_ > 0.f) && (w_ * h_ > ta + p07[k]);
            ign[k] = ign[k] || hit;
        }
    }

    float lsum = 0.f;
    #pragma unroll
    for (int k = 0; k < 2; ++k)
        if (valid[k])
            lsum += (ign[k] ? LOG2C : softplus_f(c4v[k])) + 80.f * LOG2C + whb[k];

    block_reduce_atomic(lsum, wsums, loss);
}

// ---------------- correction pass: matched-label deltas (rare path) ----------------
template<int H, int W, int STRIDE, int GROUP>
__device__ __forceinline__ void corr_part(const float* __restrict__ out,
        const float* __restrict__ tgt, float* __restrict__ loss, int bbase,
        float4 (*sbox)[N_LABELS], float (*sa)[N_LABELS], int (*slin)[64], float* wsums)
{
    constexpr int HW = H * W;
    int tid = threadIdx.x, wid = tid >> 6, lane = tid & 63;
    int b = bbase + wid;

    float tx=0, ty=0, tw=0, th=0, lw=0, lh=0, sc=0;
    int lin = -1, cls = 0;
    if (lane < N_LABELS) {
        const float* lp = tgt + ((size_t)b * N_LABELS + lane) * 5;
        cls = (int)lp[0];
        tx = lp[1] * (float)W; ty = lp[2] * (float)H;
        tw = lp[3] * (float)W; th = lp[4] * (float)H;
        float ta = tw * th;
        sbox[wid][lane] = make_float4(tx - 0.5f*tw, ty - 0.5f*th, tx + 0.5f*tw, ty + 0.5f*th);
        sa[wid][lane] = ta * (0.7f / 1.7f);
        float best_iou = -1.f; int best = 0;
        #pragma unroll
        for (int kk = 0; kk < 9; ++kk) {
            float rw = d_anchors[kk][0] * (1.f / (float)STRIDE);
            float rh = d_anchors[kk][1] * (1.f / (float)STRIDE);
            float mx = fminf(tw, rw), my = fminf(th, rh);
            float inter = (mx > 0.f && my > 0.f) ? mx * my : 0.f;
            float iou = inter / (ta + rw * rh - inter);
            if (iou > best_iou) { best_iou = iou; best = kk; }
        }
        int bn = best - (best / 3) * 3;
        float aw = d_anchors[GROUP*3 + bn][0] * (1.f / (float)STRIDE);
        float ah = d_anchors[GROUP*3 + bn][1] * (1.f / (float)STRIDE);
        lw = __logf(tw / aw + 1e-16f);
        lh = __logf(th / ah + 1e-16f);
        sc = sqrtf(2.f - tw * th * (1.f / (float)HW));
        if (best / 3 == GROUP) {
            int ti = (int)tx, tj = (int)ty;
            lin = (bn * H + tj) * W + ti;
        }
    }
    slin[wid][lane] = lin;
    __syncthreads();

    bool active = (lin >= 0);
    if (active) {                       // last-write-wins on duplicate cells
        for (int l2 = lane + 1; l2 < N_LABELS; ++l2)
            if (slin[wid][l2] == lin) active = false;
    }

    float lsum = 0.f;
    if (active) {
        int a = lin / HW, rem = lin - a * HW;
        int hh = rem / W, ww = rem - hh * W;
        const float* base = out + ((size_t)b * 255 + (size_t)a * 85) * HW + rem;
        float c0 = base[0];
        float c1 = base[HW];
        float c2 = base[2 * (size_t)HW];
        float c3 = base[3 * (size_t)HW];
        float c4 = base[4 * (size_t)HW];
        float aw = d_anchors[GROUP*3 + a][0] * (1.f / (float)STRIDE);
        float ah = d_anchors[GROUP*3 + a][1] * (1.f / (float)STRIDE);
        float pw = __expf(c2) * aw, ph = __expf(c3) * ah;
        float px = sigmoid_f(c0) + (float)ww;
        float py = sigmoid_f(c1) + (float)hh;
        float X0 = px - 0.5f*pw, X1 = px + 0.5f*pw;
        float Y0 = py - 0.5f*ph, Y1 = py + 0.5f*ph;
        float p07 = pw * ph * (0.7f / 1.7f);
        bool ign = false;
        for (int l = 0; l < N_LABELS; ++l) {
            float4 tb = sbox[wid][l];
            float ta = sa[wid][l];
            float w_ = fminf(X1, tb.z) - fmaxf(X0, tb.x);
            float h_ = fminf(Y1, tb.w) - fmaxf(Y0, tb.y);
            ign = ign || ((w_ > 0.f) && (h_ > 0.f) && (w_ * h_ > ta + p07));
        }
        float baseobj = ign ? LOG2C : softplus_f(c4);   // what main_part added for obj
        lsum += bce_f(c4, 1.f) - baseobj;
        float s2 = sc * sc;
        float txf = tx - (float)(int)tx, tyf = ty - (float)(int)ty;
        lsum += (bce_f(c0, txf) + bce_f(c1, tyf)) * s2;
        float dw = c2 - lw, dh = c3 - lh;
        lsum += 0.5f * (dw*dw + dh*dh) * s2;
        float csum = 0.f;
        for (int c = 0; c < NCLS; ++c) {
            float lg = base[(size_t)(5 + c) * HW];
            csum += bce_f(lg, (c == cls) ? 1.f : 0.f);
        }
        lsum += csum - 80.f * LOG2C;
    }

    block_reduce_atomic(lsum, wsums, loss);
}

// Grid: L0: 3 chunks x16 = 48 | L1: 9x16 = 144 | L2: 34x16 = 544 | corr: 12  => 748
__global__ __launch_bounds__(256) void yolo_main(
        const float* __restrict__ o0, const float* __restrict__ o1,
        const float* __restrict__ o2, const float* __restrict__ tgt,
        float* __restrict__ loss)
{
    __shared__ float4 sbox[4][N_LABELS];
    __shared__ float  sa[4][N_LABELS];
    __shared__ int    slin[4][64];
    __shared__ float  wsums[4];
    int bid = blockIdx.x;
    if (bid < 48) {
        main_part<19,19,32,2>(o0, tgt, loss, bid / 3, bid % 3, &sbox[0][0], &sa[0][0], wsums);
    } else if (bid < 192) {
        int id = bid - 48;
        main_part<38,38,16,1>(o1, tgt, loss, id / 9, id % 9, &sbox[0][0], &sa[0][0], wsums);
    } else if (bid < 736) {
        int id = bid - 192;
        main_part<76,76,8,0>(o2, tgt, loss, id / 34, id % 34, &sbox[0][0], &sa[0][0], wsums);
    } else {
        int cb = bid - 736;                 // 0..11
        int layer = cb >> 2, bbase = (cb & 3) * 4;
        if (layer == 0)      corr_part<19,19,32,2>(o0, tgt, loss, bbase, sbox, sa, slin, wsums);
        else if (layer == 1) corr_part<38,38,16,1>(o1, tgt, loss, bbase, sbox, sa, slin, wsums);
        else                 corr_part<76,76,8,0>(o2, tgt, loss, bbase, sbox, sa, slin, wsums);
    }
}

__global__ void zero_out_kernel(float* p) { *p = 0.f; }

extern "C" void kernel_launch(void* const* d_in, const int* in_sizes, int n_in,
                              void* d_out, int out_size, void* d_ws, size_t ws_size,
                              hipStream_t stream) {
    const float* o0  = (const float*)d_in[0];
    const float* o1  = (const float*)d_in[1];
    const float* o2  = (const float*)d_in[2];
    const float* tgt = (const float*)d_in[3];
    float* loss = (float*)d_out;
    zero_out_kernel<<<1, 1, 0, stream>>>(loss);
    yolo_main<<<748, 256, 0, stream>>>(o0, o1, o2, tgt, loss);
}

// Round 3
// 28.708 us; speedup vs baseline: 2.4641x; 1.1457x over previous
//
#include <hip/hip_runtime.h>
#include <math.h>

#define N_LABELS 50
#define NCLS 80
#define LOG2C 0.693147180559945f
#define N_MAIN_BLOCKS 736
#define N_CORR_BLOCKS 12
#define N_BLOCKS (N_MAIN_BLOCKS + N_CORR_BLOCKS)

__device__ __constant__ float d_anchors[9][2] = {
    {10.f,13.f},{16.f,30.f},{33.f,23.f},{30.f,61.f},{62.f,45.f},
    {59.f,119.f},{116.f,90.f},{156.f,198.f},{373.f,326.f}
};

__device__ __forceinline__ float softplus_f(float x) {      // == bce(x, 0)
    return fmaxf(x, 0.f) + __logf(1.f + __expf(-fabsf(x)));
}
__device__ __forceinline__ float bce_f(float x, float z) {
    return fmaxf(x, 0.f) - x * z + __logf(1.f + __expf(-fabsf(x)));
}
__device__ __forceinline__ float sigmoid_f(float x) {
    return __builtin_amdgcn_rcpf(1.f + __expf(-x));
}

// returns block total in thread 0
__device__ __forceinline__ float block_reduce(float v, float* wsums) {
    #pragma unroll
    for (int off = 32; off > 0; off >>= 1)
        v += __shfl_down(v, off);
    int tid = threadIdx.x;
    if ((tid & 63) == 0) wsums[tid >> 6] = v;
    __syncthreads();
    return wsums[0] + wsums[1] + wsums[2] + wsums[3];
}

template<bool ATOMIC>
__device__ __forceinline__ void block_finish(float v, float* wsums, float* sink) {
    float tot = block_reduce(v, wsums);
    if (threadIdx.x == 0) {
        if (ATOMIC) atomicAdd(sink, tot);
        else        sink[blockIdx.x] = tot;
    }
}

// ---------------- main uniform pass: every cell, no divergence ----------------
template<int H, int W, int STRIDE, int GROUP, bool ATOMIC>
__device__ __forceinline__ void main_part(const float* __restrict__ out,
        const float* __restrict__ tgt, float* __restrict__ sink,
        int b, int chunk, float4* sbox, float* wsums)
{
    constexpr int HW = H * W;
    constexpr int NC = 3 * HW;
    int tid = threadIdx.x;

    if (tid < N_LABELS) {
        const float* lp = tgt + ((size_t)b * N_LABELS + tid) * 5;
        float tx = lp[1] * (float)W, ty = lp[2] * (float)H;
        float tw = lp[3] * (float)W, th = lp[4] * (float)H;
        sbox[tid] = make_float4(tx - 0.5f*tw, ty - 0.5f*th, tx + 0.5f*tw, ty + 0.5f*th);
    }
    __syncthreads();

    const float* ob = out + (size_t)b * 255 * HW;
    int c0i = chunk * 512 + tid;
    float x0[2], x1[2], y0[2], y1[2], p07[2], c4v[2], whb[2];
    bool valid[2], ign[2];

    #pragma unroll
    for (int k = 0; k < 2; ++k) {
        int cell = c0i + k * 256;
        valid[k] = (cell < NC);
        int cc = valid[k] ? cell : 0;
        int a = cc / HW, rem = cc - a * HW;
        int hh = rem / W, ww = rem - hh * W;
        const float* base = ob + (size_t)a * 85 * HW + rem;
        float c0 = base[0];
        float c1 = base[HW];
        float c2 = base[2 * (size_t)HW];
        float c3 = base[3 * (size_t)HW];
        c4v[k] = base[4 * (size_t)HW];
        float aw = d_anchors[GROUP*3 + a][0] * (1.f / (float)STRIDE);
        float ah = d_anchors[GROUP*3 + a][1] * (1.f / (float)STRIDE);
        float pw = __expf(c2) * aw, ph = __expf(c3) * ah;
        float px = sigmoid_f(c0) + (float)ww;
        float py = sigmoid_f(c1) + (float)hh;
        x0[k] = px - 0.5f*pw; x1[k] = px + 0.5f*pw;
        y0[k] = py - 0.5f*ph; y1[k] = py + 0.5f*ph;
        p07[k] = pw * ph * (0.7f / 1.7f);
        whb[k] = 0.5f * (c2*c2 + c3*c3);      // unmasked wh (warm-up prior) term
        ign[k] = false;
    }

    #pragma unroll 5
    for (int l = 0; l < N_LABELS; ++l) {
        float4 tb = sbox[l];
        float ta07 = (tb.z - tb.x) * (tb.w - tb.y) * (0.7f / 1.7f);
        #pragma unroll
        for (int k = 0; k < 2; ++k) {
            float w_ = fminf(x1[k], tb.z) - fmaxf(x0[k], tb.x);
            float h_ = fminf(y1[k], tb.w) - fmaxf(y0[k], tb.y);
            // iou > 0.7  <=>  inter > 0.7/1.7 * (parea + tarea)   (no division)
            bool hit = (fminf(w_, h_) > 0.f) && (w_ * h_ > ta07 + p07[k]);
            ign[k] = ign[k] || hit;
        }
    }

    float lsum = 0.f;
    #pragma unroll
    for (int k = 0; k < 2; ++k)
        if (valid[k])
            lsum += (ign[k] ? LOG2C : softplus_f(c4v[k])) + 80.f * LOG2C + whb[k];

    block_finish<ATOMIC>(lsum, wsums, sink);
}

// ---------------- correction pass: matched-label deltas (rare path) ----------------
template<int H, int W, int STRIDE, int GROUP, bool ATOMIC>
__device__ __forceinline__ void corr_part(const float* __restrict__ out,
        const float* __restrict__ tgt, float* __restrict__ sink, int bbase,
        float4 (*sbox)[N_LABELS], float (*slin_f)[64], float* wsums)
{
    constexpr int HW = H * W;
    int tid = threadIdx.x, wid = tid >> 6, lane = tid & 63;
    int b = bbase + wid;
    int* slin = (int*)slin_f;

    float tx=0, ty=0, tw=0, th=0, lw=0, lh=0, sc=0;
    int lin = -1, cls = 0;
    if (lane < N_LABELS) {
        const float* lp = tgt + ((size_t)b * N_LABELS + lane) * 5;
        cls = (int)lp[0];
        tx = lp[1] * (float)W; ty = lp[2] * (float)H;
        tw = lp[3] * (float)W; th = lp[4] * (float)H;
        float ta = tw * th;
        sbox[wid][lane] = make_float4(tx - 0.5f*tw, ty - 0.5f*th, tx + 0.5f*tw, ty + 0.5f*th);
        float best_iou = -1.f; int best = 0;
        #pragma unroll
        for (int kk = 0; kk < 9; ++kk) {
            float rw = d_anchors[kk][0] * (1.f / (float)STRIDE);
            float rh = d_anchors[kk][1] * (1.f / (float)STRIDE);
            float mx = fminf(tw, rw), my = fminf(th, rh);
            float inter = (mx > 0.f && my > 0.f) ? mx * my : 0.f;
            float iou = inter / (ta + rw * rh - inter);
            if (iou > best_iou) { best_iou = iou; best = kk; }
        }
        int bn = best - (best / 3) * 3;
        float aw = d_anchors[GROUP*3 + bn][0] * (1.f / (float)STRIDE);
        float ah = d_anchors[GROUP*3 + bn][1] * (1.f / (float)STRIDE);
        lw = __logf(tw / aw + 1e-16f);
        lh = __logf(th / ah + 1e-16f);
        sc = sqrtf(2.f - tw * th * (1.f / (float)HW));
        if (best / 3 == GROUP) {
            int ti = (int)tx, tj = (int)ty;
            lin = (bn * H + tj) * W + ti;
        }
    }
    slin[wid * 64 + lane] = lin;
    __syncthreads();

    bool active = (lin >= 0);
    if (active) {                       // last-write-wins on duplicate cells
        for (int l2 = lane + 1; l2 < N_LABELS; ++l2)
            if (slin[wid * 64 + l2] == lin) active = false;
    }

    float lsum = 0.f;
    if (active) {
        int a = lin / HW, rem = lin - a * HW;
        int hh = rem / W, ww = rem - hh * W;
        const float* base = out + ((size_t)b * 255 + (size_t)a * 85) * HW + rem;
        float c0 = base[0];
        float c1 = base[HW];
        float c2 = base[2 * (size_t)HW];
        float c3 = base[3 * (size_t)HW];
        float c4 = base[4 * (size_t)HW];
        float aw = d_anchors[GROUP*3 + a][0] * (1.f / (float)STRIDE);
        float ah = d_anchors[GROUP*3 + a][1] * (1.f / (float)STRIDE);
        float pw = __expf(c2) * aw, ph = __expf(c3) * ah;
        float px = sigmoid_f(c0) + (float)ww;
        float py = sigmoid_f(c1) + (float)hh;
        float X0 = px - 0.5f*pw, X1 = px + 0.5f*pw;
        float Y0 = py - 0.5f*ph, Y1 = py + 0.5f*ph;
        float p07 = pw * ph * (0.7f / 1.7f);
        bool ign = false;
        for (int l = 0; l < N_LABELS; ++l) {
            float4 tb = sbox[wid][l];
            float ta07 = (tb.z - tb.x) * (tb.w - tb.y) * (0.7f / 1.7f);
            float w_ = fminf(X1, tb.z) - fmaxf(X0, tb.x);
            float h_ = fminf(Y1, tb.w) - fmaxf(Y0, tb.y);
            ign = ign || ((fminf(w_, h_) > 0.f) && (w_ * h_ > ta07 + p07));
        }
        float baseobj = ign ? LOG2C : softplus_f(c4);   // what main_part added for obj
        lsum += bce_f(c4, 1.f) - baseobj;
        float s2 = sc * sc;
        float txf = tx - (float)(int)tx, tyf = ty - (float)(int)ty;
        lsum += (bce_f(c0, txf) + bce_f(c1, tyf)) * s2;
        float dw = c2 - lw, dh = c3 - lh;
        lsum += 0.5f * (dw*dw + dh*dh) * s2;
        float csum = 0.f;
        for (int c = 0; c < NCLS; ++c) {
            float lg = base[(size_t)(5 + c) * HW];
            csum += bce_f(lg, (c == cls) ? 1.f : 0.f);
        }
        lsum += csum - 80.f * LOG2C;
    }

    block_finish<ATOMIC>(lsum, wsums, sink);
}

// Grid: L0: 3 chunks x16 = 48 | L1: 9x16 = 144 | L2: 34x16 = 544 | corr: 12  => 748
template<bool ATOMIC>
__global__ __launch_bounds__(256) void yolo_main(
        const float* __restrict__ o0, const float* __restrict__ o1,
        const float* __restrict__ o2, const float* __restrict__ tgt,
        float* __restrict__ sink)
{
    __shared__ float4 sbox[4][N_LABELS];
    __shared__ float  slin_f[4][64];
    __shared__ float  wsums[4];
    int bid = blockIdx.x;
    if (bid < 48) {
        main_part<19,19,32,2,ATOMIC>(o0, tgt, sink, bid / 3, bid % 3, &sbox[0][0], wsums);
    } else if (bid < 192) {
        int id = bid - 48;
        main_part<38,38,16,1,ATOMIC>(o1, tgt, sink, id / 9, id % 9, &sbox[0][0], wsums);
    } else if (bid < 736) {
        int id = bid - 192;
        main_part<76,76,8,0,ATOMIC>(o2, tgt, sink, id / 34, id % 34, &sbox[0][0], wsums);
    } else {
        int cb = bid - 736;                 // 0..11
        int layer = cb >> 2, bbase = (cb & 3) * 4;
        if (layer == 0)      corr_part<19,19,32,2,ATOMIC>(o0, tgt, sink, bbase, sbox, slin_f, wsums);
        else if (layer == 1) corr_part<38,38,16,1,ATOMIC>(o1, tgt, sink, bbase, sbox, slin_f, wsums);
        else                 corr_part<76,76,8,0,ATOMIC>(o2, tgt, sink, bbase, sbox, slin_f, wsums);
    }
}

__global__ __launch_bounds__(256) void reduce_partials(const float* __restrict__ partials,
                                                       float* __restrict__ loss)
{
    int tid = threadIdx.x;
    float v = 0.f;
    for (int i = tid; i < N_BLOCKS; i += 256)
        v += partials[i];
    __shared__ float wsums[4];
    #pragma unroll
    for (int off = 32; off > 0; off >>= 1)
        v += __shfl_down(v, off);
    if ((tid & 63) == 0) wsums[tid >> 6] = v;
    __syncthreads();
    if (tid == 0) *loss = wsums[0] + wsums[1] + wsums[2] + wsums[3];
}

__global__ void zero_out_kernel(float* p) { *p = 0.f; }

extern "C" void kernel_launch(void* const* d_in, const int* in_sizes, int n_in,
                              void* d_out, int out_size, void* d_ws, size_t ws_size,
                              hipStream_t stream) {
    const float* o0  = (const float*)d_in[0];
    const float* o1  = (const float*)d_in[1];
    const float* o2  = (const float*)d_in[2];
    const float* tgt = (const float*)d_in[3];
    float* loss = (float*)d_out;
    if (ws_size >= (size_t)N_BLOCKS * sizeof(float)) {
        float* partials = (float*)d_ws;
        yolo_main<false><<<N_BLOCKS, 256, 0, stream>>>(o0, o1, o2, tgt, partials);
        reduce_partials<<<1, 256, 0, stream>>>(partials, loss);
    } else {
        zero_out_kernel<<<1, 1, 0, stream>>>(loss);
        yolo_main<true><<<N_BLOCKS, 256, 0, stream>>>(o0, o1, o2, tgt, loss);
    }
}